// Round 6
// baseline (7205.977 us; speedup 1.0000x reference)
//
#include <hip/hip_runtime.h>
#include <stdint.h>

// ---------------- problem constants ----------------
#define BSZ 64
#define TSEQ 512
#define KTAG 12
#define START_TAG 10
#define STOP_TAG 11

#define TPH 64   // timesteps per phase
#define NPH 8    // phases (TPH*NPH == TSEQ)
#define NWG 256
#define BLK 256

#define FIX_SCALE 4294967296.0
#define FIX_INV 2.3283064365386963e-10

typedef unsigned long long u64t;

// ---------------- workspace layout (bytes) ----------------
// bar: per ct (4 groups): flag at [ct*64], counter at [ct*64+16] (different cachelines)
#define BAR_BYTES 4096
#define FEATS_OFF BAR_BYTES
#define FEATS_BYTES (BSZ * TSEQ * KTAG * 8)         // 3145728 (u64 fixed-point)
#define HBUF_OFF (FEATS_OFF + FEATS_BYTES)          // 3149824
#define HBUF_BYTES (2 * 512 * 128 * 4)              // 524288 (ping-pong h [u][ch])
#define CBUF_OFF (HBUF_OFF + HBUF_BYTES)            // 3674112
#define CBUF_BYTES (NWG * 256 * 4)                  // 262144
#define BPS_OFF (CBUF_OFF + CBUF_BYTES)             // 3936256
#define BPS_BYTES (TSEQ * BSZ * KTAG)               // 393216
#define XP_OFF (BPS_OFF + BPS_BYTES)                // 4329472
#define XP_BYTES (64 * 4 * TPH * 32 * 32 * 4)       // 67108864; total ~71.5 MB

// ---------------- LSTM phase kernel LDS (float offsets) ----------------
#define LW_OFF 0        // 16384: Wh slice [e 512][32 j] quad-XOR swizzled
#define LH_OFF 16384    // 16384: h slice  [e 512][32 c] quad-XOR swizzled
#define LG_OFF 32768    // 4096 : per-wave partial gates [4][32 j][32 c]
#define LXP_OFF 36864   // 1056 : xp tile [32 c][33]
#define LHL_OFF 37920   // 256  : h local [8 uu][32 c]
#define LCS_OFF 38176   // 256  : c-state [8 uu][32 c]
#define LBI_OFF 38432   // 32   : bias
#define LWO_OFF 38464   // 96   : W_out slice [12 k][8 uu]
#define LSL_OFF 38560   // 32 ints: seq lens
#define LMX_OFF 38592   // 1 int : group max seq len
#define LSTM_SMEM_FLOATS 38596
#define LSTM_SMEM_BYTES (LSTM_SMEM_FLOATS * 4)      // 154384 < 160 KiB

// ---------------- pre-GEMM kernel LDS ----------------
#define PW_OFF 0        // 16384: Wi slice [e 512][32 j] swizzled
#define PE_OFF 16384    // 8192 : emb chunk [e 128][64 r] swizzled
#define PT_OFF 24576    // 64 ints: tokens
#define PRE_SMEM_FLOATS 24640
#define PRE_SMEM_BYTES (PRE_SMEM_FLOATS * 4)        // 98560

__device__ __forceinline__ float sigm(float x) { return 1.f / (1.f + expf(-x)); }

// ---------------- init: h0 -> hbuf slot 0, c0 -> cbuf ----------------
__global__ void init_state(const float* __restrict__ h0, const float* __restrict__ c0,
                           float* __restrict__ hbuf, float* __restrict__ cbuf) {
  int i = blockIdx.x * 256 + threadIdx.x;
  if (i < 65536) {
    int u = i >> 7, ch = i & 127;
    int ct = ch >> 5, c = ch & 31;
    int dir = ct >> 1, b = ((ct & 1) << 5) + c;
    hbuf[i] = h0[(dir * 64 + b) * 512 + u];
  } else {
    int j = i - 65536;
    int wg = j >> 8, r = j & 255;
    int ct = wg >> 6, ut = wg & 63;
    int uu = r >> 5, c = r & 31;
    int dir = ct >> 1, b = ((ct & 1) << 5) + c;
    cbuf[j] = c0[(dir * 64 + b) * 512 + ut * 8 + uu];
  }
}

// ---------------- pre-GEMM: one WG = (dir,ut) x 8 batch rows; Wi staged once ----------------
// xp[ut][ct][taul][c][j] = emb(b, pos(tau)) @ Wi_slice
__global__ __launch_bounds__(256, 1) void pre_gemm(
    int phase, const int* __restrict__ sentence, const int* __restrict__ seq_lens,
    const float* __restrict__ embed, const float* __restrict__ Wi_f,
    const float* __restrict__ Wi_b, float* __restrict__ xp) {
  extern __shared__ float sm[];
  float* wiS = sm + PW_OFF;
  float* embS = sm + PE_OFF;
  int* tokS = (int*)(sm + PT_OFF);

  const int tid = threadIdx.x;
  const int dirut = blockIdx.x;            // 128
  const int dir = dirut >> 6, ut = dirut & 63;
  const int yo = blockIdx.y;               // 8 octets of batch rows
  const int t0 = phase * TPH;
  if (t0 >= seq_lens[yo * 8]) return;      // sorted desc -> whole octet masked
  const int u0 = ut * 8;
  const float* Wi = dir ? Wi_b : Wi_f;

  // stage Wi slice ONCE for all 8 batch rows
  for (int j = 0; j < 32; ++j) {
    int row = (j >> 3) * 512 + u0 + (j & 7);
    for (int ee = tid; ee < 512; ee += BLK)
      wiS[ee * 32 + ((((j >> 2) ^ (ee & 7)) << 2) | (j & 3))] = Wi[row * 512 + ee];
  }

  const int lane = tid & 63, w = tid >> 6;
  const int es = lane >> 3, tl8 = lane & 7;
  const int tile = w * 8 + tl8;
  const int jt = tile & 3, rt = tile >> 2;
  const int rr = tid & 63, seg = tid >> 6;
  const int rq = rr >> 2, rl = rr & 3;
  const float* wp0b = wiS + (((jt * 2) ^ es) << 2) + es * 32;
  const float* wp1b = wiS + (((jt * 2 + 1) ^ es) << 2) + es * 32;
  const float* ep0 = embS + es * 64 + (((rt * 2) ^ es) << 2);
  const float* ep1 = embS + es * 64 + (((rt * 2 + 1) ^ es) << 2);
  const bool hi1 = (lane & 8) != 0;
  const bool hi2 = (lane & 16) != 0;
  const bool hi3 = (lane & 32) != 0;
  const int ab1 = hi1 ? 4 : 0, bb = hi2 ? 4 : 0, ab2 = hi3 ? 2 : 0;

  for (int ib = 0; ib < 8; ++ib) {
    const int b = yo * 8 + ib;
    const int sl = seq_lens[b];
    if (t0 >= sl) break;                   // sorted desc within octet
    const int ct = dir * 2 + (b >> 5);
    const int cc = b & 31;

    __syncthreads();                       // prior iter's embS/tokS reads done
    if (tid < 64) {
      int tg = t0 + tid;
      int pos = dir ? (sl - 1 - tg) : tg;
      pos = min(max(pos, 0), 511);
      tokS[tid] = sentence[b * 512 + pos];
    }
    __syncthreads();

    const int mytok = tokS[rr];
    float4 vb[2][8];
    {
      const float* src = embed + (size_t)mytok * 512 + seg * 32;
#pragma unroll
      for (int q = 0; q < 8; ++q) vb[0][q] = *(const float4*)(src + q * 4);
    }
    float acc[8][8];
#pragma unroll
    for (int a = 0; a < 8; ++a)
#pragma unroll
      for (int b2 = 0; b2 < 8; ++b2) acc[a][b2] = 0.f;

#pragma unroll
    for (int kk = 0; kk < 4; ++kk) {
      if (kk) __syncthreads();
#pragma unroll
      for (int q = 0; q < 8; ++q) {
        const int el = seg * 32 + q * 4;
        const float4 v = vb[kk & 1][q];
        embS[(el + 0) * 64 + (((rq ^ ((el + 0) & 7)) << 2) | rl)] = v.x;
        embS[(el + 1) * 64 + (((rq ^ ((el + 1) & 7)) << 2) | rl)] = v.y;
        embS[(el + 2) * 64 + (((rq ^ ((el + 2) & 7)) << 2) | rl)] = v.z;
        embS[(el + 3) * 64 + (((rq ^ ((el + 3) & 7)) << 2) | rl)] = v.w;
      }
      if (kk < 3) {
        const float* src = embed + (size_t)mytok * 512 + (kk + 1) * 128 + seg * 32;
#pragma unroll
        for (int q = 0; q < 8; ++q) vb[(kk + 1) & 1][q] = *(const float4*)(src + q * 4);
      }
      __syncthreads();
      const float* wp0 = wp0b + kk * 128 * 32;
      const float* wp1 = wp1b + kk * 128 * 32;
#pragma unroll
      for (int i = 0; i < 16; ++i) {
        const float4 w0 = *(const float4*)(wp0 + i * 256);
        const float4 w1 = *(const float4*)(wp1 + i * 256);
        const float4 x0 = *(const float4*)(ep0 + i * 512);
        const float4 x1 = *(const float4*)(ep1 + i * 512);
        float wv[8] = {w0.x, w0.y, w0.z, w0.w, w1.x, w1.y, w1.z, w1.w};
        float xv[8] = {x0.x, x0.y, x0.z, x0.w, x1.x, x1.y, x1.z, x1.w};
#pragma unroll
        for (int a = 0; a < 8; ++a)
#pragma unroll
          for (int b2 = 0; b2 < 8; ++b2) acc[a][b2] = fmaf(wv[a], xv[b2], acc[a][b2]);
      }
    }

    // butterfly reduce-scatter over es lane-bits 8,16,32
    float r1[4][8];
#pragma unroll
    for (int a = 0; a < 4; ++a)
#pragma unroll
      for (int b2 = 0; b2 < 8; ++b2) {
        float sendv = hi1 ? acc[a][b2] : acc[a + 4][b2];
        float keepv = hi1 ? acc[a + 4][b2] : acc[a][b2];
        r1[a][b2] = keepv + __shfl_xor(sendv, 8, 64);
      }
    float r2[4][4];
#pragma unroll
    for (int a = 0; a < 4; ++a)
#pragma unroll
      for (int b2 = 0; b2 < 4; ++b2) {
        float sendv = hi2 ? r1[a][b2] : r1[a][b2 + 4];
        float keepv = hi2 ? r1[a][b2 + 4] : r1[a][b2];
        r2[a][b2] = keepv + __shfl_xor(sendv, 16, 64);
      }
    float r3[2][4];
#pragma unroll
    for (int a = 0; a < 2; ++a)
#pragma unroll
      for (int b2 = 0; b2 < 4; ++b2) {
        float sendv = hi3 ? r2[a][b2] : r2[a + 2][b2];
        float keepv = hi3 ? r2[a + 2][b2] : r2[a][b2];
        r3[a][b2] = keepv + __shfl_xor(sendv, 32, 64);
      }
    const size_t base = (size_t)(ut * 4 + ct) * (TPH * 1024) + (size_t)cc * 32;
#pragma unroll
    for (int a = 0; a < 2; ++a)
#pragma unroll
      for (int b2 = 0; b2 < 4; ++b2) {
        int tau = rt * 8 + bb + b2;
        if (t0 + tau < sl)
          xp[base + (size_t)tau * 1024 + (jt * 8 + ab1 + ab2 + a)] = r3[a][b2];
      }
  }
}

// ---------------- LSTM recurrent phase (cooperative, 256 WGs) ----------------
// Fence-free h exchange (write-through agent stores + L2-bypass agent loads) with
// all-wave flag polling and chunked h-load/compute overlap.
__global__ __launch_bounds__(BLK, 1) void lstm_phase(
    int phase, const int* __restrict__ seq_lens, const float* __restrict__ Wh_f,
    const float* __restrict__ Wh_b, const float* __restrict__ b_f,
    const float* __restrict__ b_b, const float* __restrict__ W_out,
    const float* __restrict__ xp, float* __restrict__ hbuf, float* __restrict__ cbuf,
    unsigned long long* __restrict__ featsFix, unsigned* __restrict__ bar) {
  extern __shared__ float sm[];
  float* wS = sm + LW_OFF;
  float* hS = sm + LH_OFF;
  float* gS = sm + LG_OFF;
  float* xpS = sm + LXP_OFF;
  float* hlS = sm + LHL_OFF;
  float* cstS = sm + LCS_OFF;
  float* biasS = sm + LBI_OFF;
  float* woutS = sm + LWO_OFF;
  int* slS = (int*)(sm + LSL_OFF);
  int* mslS = (int*)(sm + LMX_OFF);

  const int tid = threadIdx.x;
  const int bid = blockIdx.x;
  const int ut = bid & 63, ct = bid >> 6;
  const int u0 = ut * 8, ch0 = ct * 32, dir = ct >> 1;
  const float* Wh = dir ? Wh_b : Wh_f;
  const float* bb = dir ? b_b : b_f;

  if (tid < 32) slS[tid] = seq_lens[((ct & 1) << 5) + tid];
  __syncthreads();
  if (tid == 0) {
    int m = 0;
    for (int c = 0; c < 32; ++c) m = max(m, slS[c]);
    *mslS = m;
  }
  __syncthreads();
  const int gmax = *mslS;
  const int t0 = phase * TPH;
  if (t0 >= gmax) return;  // group-uniform exit

  for (int j = 0; j < 32; ++j) {
    int row = (j >> 3) * 512 + u0 + (j & 7);
    for (int ee = tid; ee < 512; ee += BLK)
      wS[ee * 32 + ((((j >> 2) ^ (ee & 7)) << 2) | (j & 3))] = Wh[row * 512 + ee];
  }
  if (tid < 96) woutS[tid] = W_out[(tid >> 3) * 1024 + dir * 512 + u0 + (tid & 7)];
  if (tid < 32) biasS[tid] = bb[(tid >> 3) * 512 + u0 + (tid & 7)];
  cstS[tid] = cbuf[bid * 256 + tid];
  __syncthreads();

  const int lane = tid & 63, w = tid >> 6;
  const int tp = lane & 15, jt = tp & 3, ct2 = tp >> 2;
  const int es = w * 4 + (lane >> 4);
  const int esw = es & 7;
  const int nst = min(TPH, gmax - t0);

  const float* wpA = wS + es * 32 + (((jt * 2) ^ esw) << 2);
  const float* wpB = wS + es * 32 + (((jt * 2 + 1) ^ esw) << 2);
  const float* hpA = hS + es * 32 + (((ct2 * 2) ^ esw) << 2);
  const float* hpB = hS + es * 32 + (((ct2 * 2 + 1) ^ esw) << 2);

  float4 xr = *(const float4*)(xp + ((size_t)(ut * 4 + ct) * TPH + 0) * 1024 + tid * 4);

  for (int tl = 0; tl < nst; ++tl) {
    const int t = t0 + tl;
    const float* hcur = hbuf + (t & 1) * 65536;
    float* hnxt = hbuf + ((t + 1) & 1) * 65536;

    // ---- wait: all waves spin on the broadcast flag (wave-uniform -> 1 req/wave) ----
    {
      const unsigned tgt = (unsigned)t;
      while (__hip_atomic_load(&bar[ct * 64], __ATOMIC_RELAXED,
                               __HIP_MEMORY_SCOPE_AGENT) < tgt) {}
    }

    // [A] issue ALL h loads up-front (L2-bypass); stage xp; prefetch next xp
    u64t hq[32];
#pragma unroll
    for (int it = 0; it < 16; ++it) {
      int u = it * 32 + (tid >> 3), q = tid & 7;
      const u64t* p = (const u64t*)(hcur + u * 128 + ch0 + q * 4);
      hq[2 * it] = __hip_atomic_load(p, __ATOMIC_RELAXED, __HIP_MEMORY_SCOPE_AGENT);
      hq[2 * it + 1] =
          __hip_atomic_load(p + 1, __ATOMIC_RELAXED, __HIP_MEMORY_SCOPE_AGENT);
    }
    {
      int c = tid >> 3, j4 = tid & 7;
      float* d = xpS + c * 33 + j4 * 4;
      d[0] = xr.x; d[1] = xr.y; d[2] = xr.z; d[3] = xr.w;
    }
    if (tl + 1 < nst)
      xr = *(const float4*)(xp + ((size_t)(ut * 4 + ct) * TPH + (tl + 1)) * 1024 + tid * 4);

    // [B] chunked: per 128-e chunk {ds_write, sync, compute} — compute(ck) overlaps
    // the in-flight loads of chunks ck+1..3
    float acc[8][8];
#pragma unroll
    for (int a = 0; a < 8; ++a)
#pragma unroll
      for (int b2 = 0; b2 < 8; ++b2) acc[a][b2] = 0.f;
#pragma unroll
    for (int ck = 0; ck < 4; ++ck) {
#pragma unroll
      for (int it = 4 * ck; it < 4 * ck + 4; ++it) {
        int u = it * 32 + (tid >> 3), q = tid & 7;
        union { u64t q2[2]; float4 v; } uu2;
        uu2.q2[0] = hq[2 * it];
        uu2.q2[1] = hq[2 * it + 1];
        *(float4*)(hS + u * 32 + ((q ^ (u & 7)) << 2)) = uu2.v;
      }
      __syncthreads();
#pragma unroll
      for (int ii = 0; ii < 8; ++ii) {
        const int off = (ck * 8 + ii) * 512;
        const float4 w0 = *(const float4*)(wpA + off);
        const float4 w1 = *(const float4*)(wpB + off);
        const float4 x0 = *(const float4*)(hpA + off);
        const float4 x1 = *(const float4*)(hpB + off);
        float wv[8] = {w0.x, w0.y, w0.z, w0.w, w1.x, w1.y, w1.z, w1.w};
        float xv[8] = {x0.x, x0.y, x0.z, x0.w, x1.x, x1.y, x1.z, x1.w};
#pragma unroll
        for (int a = 0; a < 8; ++a)
#pragma unroll
          for (int b2 = 0; b2 < 8; ++b2) acc[a][b2] = fmaf(wv[a], xv[b2], acc[a][b2]);
      }
    }

    // in-wave butterfly reduce-scatter over es lane-bits 16,32
    const bool hi1 = (lane & 16) != 0;
    float r1[4][8];
#pragma unroll
    for (int a = 0; a < 4; ++a)
#pragma unroll
      for (int b2 = 0; b2 < 8; ++b2) {
        float sendv = hi1 ? acc[a][b2] : acc[a + 4][b2];
        float keepv = hi1 ? acc[a + 4][b2] : acc[a][b2];
        r1[a][b2] = keepv + __shfl_xor(sendv, 16, 64);
      }
    const bool hi2 = (lane & 32) != 0;
    float r2[4][4];
#pragma unroll
    for (int a = 0; a < 4; ++a)
#pragma unroll
      for (int b2 = 0; b2 < 4; ++b2) {
        float sendv = hi2 ? r1[a][b2] : r1[a][b2 + 4];
        float keepv = hi2 ? r1[a][b2 + 4] : r1[a][b2];
        r2[a][b2] = keepv + __shfl_xor(sendv, 32, 64);
      }
    const int ab = hi1 ? 4 : 0, bbs = hi2 ? 4 : 0;
#pragma unroll
    for (int a = 0; a < 4; ++a) {
      float4 v = make_float4(r2[a][0], r2[a][1], r2[a][2], r2[a][3]);
      *(float4*)(gS + w * 1024 + (jt * 8 + ab + a) * 32 + ct2 * 8 + bbs) = v;
    }
    __syncthreads();

    // [C] epilogue: combine 4 wave-partials + xp + bias -> gates -> c,h
    {
      const int uu = tid >> 5, c = tid & 31;
      const int slc = slS[c];
      float s0 = 0.f, s1 = 0.f, s2 = 0.f, s3 = 0.f;
#pragma unroll
      for (int w2 = 0; w2 < 4; ++w2) {
        const float* gp = gS + w2 * 1024 + uu * 32 + c;
        s0 += gp[0];
        s1 += gp[256];
        s2 += gp[512];
        s3 += gp[768];
      }
      const bool xvalid = (t < slc);
      float x0 = xvalid ? xpS[c * 33 + uu] : 0.f;
      float x1 = xvalid ? xpS[c * 33 + 8 + uu] : 0.f;
      float x2 = xvalid ? xpS[c * 33 + 16 + uu] : 0.f;
      float x3 = xvalid ? xpS[c * 33 + 24 + uu] : 0.f;
      float iv = s0 + x0 + biasS[uu];
      float fv = s1 + x1 + biasS[8 + uu];
      float gv = s2 + x2 + biasS[16 + uu];
      float ov = s3 + x3 + biasS[24 + uu];
      float cn = sigm(fv) * cstS[uu * 32 + c] + sigm(iv) * tanhf(gv);
      float hn = sigm(ov) * tanhf(cn);
      cstS[uu * 32 + c] = cn;
      // write-through agent store: publishes h without wbl2
      __hip_atomic_store(&hnxt[(u0 + uu) * 128 + ch0 + c], hn, __ATOMIC_RELAXED,
                         __HIP_MEMORY_SCOPE_AGENT);
      hlS[uu * 32 + c] = hn;
    }
    // drain this wave's h stores to the coherence point, then block-wide sync
    asm volatile("s_waitcnt vmcnt(0)" ::: "memory");
    __syncthreads();

    // ---- arrive: counter RMW + broadcast flag (relaxed agent; no release fence) ----
    if (tid == 0) {
      unsigned o = __hip_atomic_fetch_add(&bar[ct * 64 + 16], 1u, __ATOMIC_RELAXED,
                                          __HIP_MEMORY_SCOPE_AGENT);
      if (o == (unsigned)(t + 1) * 64u - 1u)
        __hip_atomic_store(&bar[ct * 64], (unsigned)(t + 1), __ATOMIC_RELAXED,
                           __HIP_MEMORY_SCOPE_AGENT);
    }

    // feats partial (fixed-point atomics) — issued after arrive, drains during next poll
    for (int base = 0; base < 384; base += 256) {
      int idx = base + tid;
      if (idx < 384) {
        int c = idx / 12, k = idx % 12;
        int sl = slS[c];
        if (t < sl) {
          float pacc = 0.f;
#pragma unroll
          for (int uu = 0; uu < 8; ++uu) pacc += hlS[uu * 32 + c] * woutS[k * 8 + uu];
          int tt = dir ? (sl - 1 - t) : t;
          double y = (double)pacc * FIX_SCALE;
          long long q = (long long)(y + (y >= 0.0 ? 0.5 : -0.5));
          atomicAdd(&featsFix[((size_t)(((ct & 1) << 5) + c) * 512 + tt) * 12 + k],
                    (unsigned long long)q);
        }
      }
    }
  }
  cbuf[bid * 256 + tid] = cstS[tid];
}

// ---------------- viterbi: 64 blocks (one b each), fv replicated via shfl ----------------
__global__ __launch_bounds__(64) void viterbi2(
    const int* __restrict__ seq_lens, const float* __restrict__ b_out,
    const float* __restrict__ transitions,
    const unsigned long long* __restrict__ featsFix,
    unsigned char* __restrict__ bps, float* __restrict__ out) {
  __shared__ unsigned char tagB[512];
  const int b = blockIdx.x;
  const int lane = threadIdx.x;
  const int k = lane < 12 ? lane : 0;
  const int sl = seq_lens[b];
  float trow[12];
#pragma unroll
  for (int p = 0; p < 12; ++p) trow[p] = transitions[k * 12 + p];
  const float bo = b_out[k];
  float fvv[12];
#pragma unroll
  for (int p = 0; p < 12; ++p) fvv[p] = (p == START_TAG) ? 0.f : -10000.f;
  const unsigned long long* fbase = featsFix + (size_t)b * 512 * 12;
  long long fx = (long long)fbase[k];
  for (int t = 0; t < TSEQ; ++t) {
    float best = fvv[0] + trow[0];
    int arg = 0;
#pragma unroll
    for (int p = 1; p < 12; ++p) {
      float v = fvv[p] + trow[p];
      if (v > best) { best = v; arg = p; }
    }
    float feat = (float)((double)fx * FIX_INV) + bo;
    if (t + 1 < TSEQ) fx = (long long)fbase[(t + 1) * 12 + k];
    const bool m = t < sl;
    float nv = m ? (best + feat) : fvv[k];
    int bpv = m ? arg : k;
    if (lane < 12) bps[((size_t)t * 64 + b) * 12 + lane] = (unsigned char)bpv;
#pragma unroll
    for (int p = 0; p < 12; ++p) fvv[p] = __shfl(nv, p, 64);
  }
  __syncthreads();
  if (lane == 0) {
    float best = fvv[0] + transitions[STOP_TAG * 12 + 0];
    int arg = 0;
    for (int kk = 1; kk < 12; ++kk) {
      float v = fvv[kk] + transitions[STOP_TAG * 12 + kk];
      if (v > best) { best = v; arg = kk; }
    }
    out[b] = best;
    int tag = arg;
    const uint32_t* rowp = (const uint32_t*)bps;
    uint32_t r0, r1, r2;
    {
      size_t off = ((size_t)511 * 64 + b) * 3;
      r0 = rowp[off]; r1 = rowp[off + 1]; r2 = rowp[off + 2];
    }
    for (int t = 511; t >= 0; --t) {
      uint32_t n0 = 0, n1 = 0, n2 = 0;
      if (t > 0) {
        size_t off = ((size_t)(t - 1) * 64 + b) * 3;
        n0 = rowp[off]; n1 = rowp[off + 1]; n2 = rowp[off + 2];
      }
      tagB[t] = (unsigned char)tag;
      uint32_t sel = (tag < 4) ? (r0 >> (tag * 8))
                   : (tag < 8) ? (r1 >> ((tag - 4) * 8))
                               : (r2 >> ((tag - 8) * 8));
      tag = (int)(sel & 0xffu);
      r0 = n0; r1 = n1; r2 = n2;
    }
  }
  __syncthreads();
  for (int t = lane; t < 512; t += 64) out[64 + (size_t)b * 512 + t] = (float)tagB[t];
}

extern "C" void kernel_launch(void* const* d_in, const int* in_sizes, int n_in,
                              void* d_out, int out_size, void* d_ws, size_t ws_size,
                              hipStream_t stream) {
  (void)in_sizes; (void)n_in; (void)out_size; (void)ws_size;
  const int* sentence = (const int*)d_in[0];
  const int* seq_lens = (const int*)d_in[1];
  const float* embed = (const float*)d_in[2];
  const float* Wi_f = (const float*)d_in[3];
  const float* Wh_f = (const float*)d_in[4];
  const float* b_f = (const float*)d_in[5];
  const float* Wi_b = (const float*)d_in[6];
  const float* Wh_b = (const float*)d_in[7];
  const float* b_b = (const float*)d_in[8];
  const float* h0 = (const float*)d_in[9];
  const float* c0 = (const float*)d_in[10];
  const float* W_out = (const float*)d_in[11];
  const float* b_out = (const float*)d_in[12];
  const float* trans = (const float*)d_in[13];

  char* ws = (char*)d_ws;
  unsigned* bar = (unsigned*)ws;
  unsigned long long* featsFix = (unsigned long long*)(ws + FEATS_OFF);
  float* hbuf = (float*)(ws + HBUF_OFF);
  float* cbuf = (float*)(ws + CBUF_OFF);
  unsigned char* bps = (unsigned char*)(ws + BPS_OFF);
  float* xpw = (float*)(ws + XP_OFF);

  hipMemsetAsync(d_ws, 0, FEATS_OFF + FEATS_BYTES, stream);  // bar + featsFix

  hipFuncSetAttribute((const void*)lstm_phase,
                      hipFuncAttributeMaxDynamicSharedMemorySize, LSTM_SMEM_BYTES);
  hipFuncSetAttribute((const void*)pre_gemm,
                      hipFuncAttributeMaxDynamicSharedMemorySize, PRE_SMEM_BYTES);

  init_state<<<dim3(512), dim3(256), 0, stream>>>(h0, c0, hbuf, cbuf);

  for (int p = 0; p < NPH; ++p) {
    pre_gemm<<<dim3(128, 8), dim3(BLK), PRE_SMEM_BYTES, stream>>>(
        p, sentence, seq_lens, embed, Wi_f, Wi_b, xpw);
    int pv = p;
    void* kargs[] = {(void*)&pv,    (void*)&seq_lens, (void*)&Wh_f,     (void*)&Wh_b,
                     (void*)&b_f,   (void*)&b_b,      (void*)&W_out,    (void*)&xpw,
                     (void*)&hbuf,  (void*)&cbuf,     (void*)&featsFix, (void*)&bar};
    hipLaunchCooperativeKernel((const void*)lstm_phase, dim3(NWG), dim3(BLK), kargs,
                               LSTM_SMEM_BYTES, stream);
  }
  viterbi2<<<dim3(64), dim3(64), 0, stream>>>(seq_lens, b_out, trans, featsFix, bps,
                                              (float*)d_out);
}

// Round 7
// 6128.660 us; speedup vs baseline: 1.1758x; 1.1758x over previous
//
#include <hip/hip_runtime.h>
#include <stdint.h>

// ---------------- problem constants ----------------
#define BSZ 64
#define TSEQ 512
#define KTAG 12
#define START_TAG 10
#define STOP_TAG 11

#define TPH 64   // timesteps per phase
#define NPH 8    // phases (TPH*NPH == TSEQ)
#define NWG 256
#define BLK 256

#define FIX_SCALE 4294967296.0
#define FIX_INV 2.3283064365386963e-10

typedef unsigned long long u64t;

// ---------------- workspace layout (bytes) ----------------
// bar: per ct (4 groups): flag at [ct*64], counter at [ct*64+16] (different cachelines)
#define BAR_BYTES 4096
#define FEATS_OFF BAR_BYTES
#define FEATS_BYTES (BSZ * TSEQ * KTAG * 8)         // 3145728 (u64 fixed-point)
#define HBUF_OFF (FEATS_OFF + FEATS_BYTES)          // 3149824
#define HBUF_BYTES (2 * 512 * 128 * 4)              // 524288 (ping-pong h [u][ch])
#define CBUF_OFF (HBUF_OFF + HBUF_BYTES)            // 3674112
#define CBUF_BYTES (NWG * 256 * 4)                  // 262144
#define BPS_OFF (CBUF_OFF + CBUF_BYTES)             // 3936256
#define BPS_BYTES (TSEQ * BSZ * KTAG)               // 393216
#define XP_OFF (BPS_OFF + BPS_BYTES)                // 4329472
#define XP_BYTES (64 * 4 * TPH * 32 * 32 * 4)       // 67108864 (K-half 0)
#define XP2_OFF (XP_OFF + XP_BYTES)                 // 71438336
#define XP2_BYTES XP_BYTES                          // 67108864 (K-half 1); total ~139 MB

// ---------------- LSTM phase kernel LDS (float offsets) ----------------
#define LW_OFF 0        // 16384: Wh slice [e 512][32 j] quad-XOR swizzled
#define LH_OFF 16384    // 16384: h slice  [e 512][32 c] quad-XOR swizzled
#define LG_OFF 32768    // 4096 : per-wave partial gates [4][32 j][32 c]
#define LXP_OFF 36864   // 1056 : xp tile [32 c][33]
#define LHL_OFF 37920   // 256  : h local [8 uu][32 c]
#define LCS_OFF 38176   // 256  : c-state [8 uu][32 c]
#define LBI_OFF 38432   // 32   : bias
#define LWO_OFF 38464   // 96   : W_out slice [12 k][8 uu]
#define LSL_OFF 38560   // 32 ints: seq lens
#define LMX_OFF 38592   // 1 int : group max seq len
#define LSTM_SMEM_FLOATS 38596
#define LSTM_SMEM_BYTES (LSTM_SMEM_FLOATS * 4)      // 154384 < 160 KiB

// ---------------- pre-GEMM kernel LDS (K-split: 64.3 KB -> 2 WGs/CU) ----------------
#define PW_OFF 0        // 8192: Wi K-half slice [e 256][32 j] swizzled (32 KB)
#define PE_OFF 8192     // 8192: emb chunk [e 128][64 r] swizzled (32 KB)
#define PT_OFF 16384    // 64 ints: tokens
#define PRE_SMEM_FLOATS 16448
#define PRE_SMEM_BYTES (PRE_SMEM_FLOATS * 4)        // 65792

__device__ __forceinline__ float sigm(float x) { return 1.f / (1.f + expf(-x)); }

// ---------------- init: h0 -> hbuf slot 0, c0 -> cbuf ----------------
__global__ void init_state(const float* __restrict__ h0, const float* __restrict__ c0,
                           float* __restrict__ hbuf, float* __restrict__ cbuf) {
  int i = blockIdx.x * 256 + threadIdx.x;
  if (i < 65536) {
    int u = i >> 7, ch = i & 127;
    int ct = ch >> 5, c = ch & 31;
    int dir = ct >> 1, b = ((ct & 1) << 5) + c;
    hbuf[i] = h0[(dir * 64 + b) * 512 + u];
  } else {
    int j = i - 65536;
    int wg = j >> 8, r = j & 255;
    int ct = wg >> 6, ut = wg & 63;
    int uu = r >> 5, c = r & 31;
    int dir = ct >> 1, b = ((ct & 1) << 5) + c;
    cbuf[j] = c0[(dir * 64 + b) * 512 + ut * 8 + uu];
  }
}

// ---------------- pre-GEMM: K-split (kh in {0,1}), one WG = (kh,dir,ut) x 8 b rows ----------------
// kh=0: xp[ut][ct][taul][c][j] = emb(b,pos)[0:256] @ Wi_slice[:,0:256]
// kh=1: xp2 = emb[256:512] @ Wi_slice[:,256:512]; lstm adds the two halves.
__global__ __launch_bounds__(256, 2) void pre_gemm(
    int phase, const int* __restrict__ sentence, const int* __restrict__ seq_lens,
    const float* __restrict__ embed, const float* __restrict__ Wi_f,
    const float* __restrict__ Wi_b, float* __restrict__ xp, float* __restrict__ xp2) {
  extern __shared__ float sm[];
  float* wiS = sm + PW_OFF;
  float* embS = sm + PE_OFF;
  int* tokS = (int*)(sm + PT_OFF);

  const int tid = threadIdx.x;
  const int bx = blockIdx.x;               // 256: kh*128 + dirut
  const int kh = bx >> 7;
  const int dirut = bx & 127;
  const int dir = dirut >> 6, ut = dirut & 63;
  const int yo = blockIdx.y;               // 8 octets of batch rows
  const int t0 = phase * TPH;
  if (t0 >= seq_lens[yo * 8]) return;      // sorted desc -> whole octet masked
  const int u0 = ut * 8;
  const int e0 = kh * 256;
  const float* Wi = dir ? Wi_b : Wi_f;
  float* dst = kh ? xp2 : xp;

  // stage Wi K-half slice ONCE for all 8 batch rows
  for (int j = 0; j < 32; ++j) {
    int row = (j >> 3) * 512 + u0 + (j & 7);
    int ee = tid;  // BLK == 256 covers the half in one pass
    wiS[ee * 32 + ((((j >> 2) ^ (ee & 7)) << 2) | (j & 3))] = Wi[row * 512 + e0 + ee];
  }

  const int lane = tid & 63, w = tid >> 6;
  const int es = lane >> 3, tl8 = lane & 7;
  const int tile = w * 8 + tl8;
  const int jt = tile & 3, rt = tile >> 2;
  const int rr = tid & 63, seg = tid >> 6;
  const int rq = rr >> 2, rl = rr & 3;
  const float* wp0b = wiS + (((jt * 2) ^ es) << 2) + es * 32;
  const float* wp1b = wiS + (((jt * 2 + 1) ^ es) << 2) + es * 32;
  const float* ep0 = embS + es * 64 + (((rt * 2) ^ es) << 2);
  const float* ep1 = embS + es * 64 + (((rt * 2 + 1) ^ es) << 2);
  const bool hi1 = (lane & 8) != 0;
  const bool hi2 = (lane & 16) != 0;
  const bool hi3 = (lane & 32) != 0;
  const int ab1 = hi1 ? 4 : 0, bb = hi2 ? 4 : 0, ab2 = hi3 ? 2 : 0;

  for (int ib = 0; ib < 8; ++ib) {
    const int b = yo * 8 + ib;
    const int sl = seq_lens[b];
    if (t0 >= sl) break;                   // sorted desc within octet
    const int ct = dir * 2 + (b >> 5);
    const int cc = b & 31;

    __syncthreads();                       // prior iter's embS/tokS reads done
    if (tid < 64) {
      int tg = t0 + tid;
      int pos = dir ? (sl - 1 - tg) : tg;
      pos = min(max(pos, 0), 511);
      tokS[tid] = sentence[b * 512 + pos];
    }
    __syncthreads();

    const int mytok = tokS[rr];
    float4 vb[2][8];
    {
      const float* src = embed + (size_t)mytok * 512 + e0 + seg * 32;
#pragma unroll
      for (int q = 0; q < 8; ++q) vb[0][q] = *(const float4*)(src + q * 4);
    }
    float acc[8][8];
#pragma unroll
    for (int a = 0; a < 8; ++a)
#pragma unroll
      for (int b2 = 0; b2 < 8; ++b2) acc[a][b2] = 0.f;

#pragma unroll
    for (int kk = 0; kk < 2; ++kk) {       // 2 x 128-e chunks (K-half = 256)
      if (kk) __syncthreads();
#pragma unroll
      for (int q = 0; q < 8; ++q) {
        const int el = seg * 32 + q * 4;
        const float4 v = vb[kk & 1][q];
        embS[(el + 0) * 64 + (((rq ^ ((el + 0) & 7)) << 2) | rl)] = v.x;
        embS[(el + 1) * 64 + (((rq ^ ((el + 1) & 7)) << 2) | rl)] = v.y;
        embS[(el + 2) * 64 + (((rq ^ ((el + 2) & 7)) << 2) | rl)] = v.z;
        embS[(el + 3) * 64 + (((rq ^ ((el + 3) & 7)) << 2) | rl)] = v.w;
      }
      if (kk < 1) {
        const float* src = embed + (size_t)mytok * 512 + e0 + 128 + seg * 32;
#pragma unroll
        for (int q = 0; q < 8; ++q) vb[(kk + 1) & 1][q] = *(const float4*)(src + q * 4);
      }
      __syncthreads();
      const float* wp0 = wp0b + kk * 128 * 32;
      const float* wp1 = wp1b + kk * 128 * 32;
#pragma unroll
      for (int i = 0; i < 16; ++i) {
        const float4 w0 = *(const float4*)(wp0 + i * 256);
        const float4 w1 = *(const float4*)(wp1 + i * 256);
        const float4 x0 = *(const float4*)(ep0 + i * 512);
        const float4 x1 = *(const float4*)(ep1 + i * 512);
        float wv[8] = {w0.x, w0.y, w0.z, w0.w, w1.x, w1.y, w1.z, w1.w};
        float xv[8] = {x0.x, x0.y, x0.z, x0.w, x1.x, x1.y, x1.z, x1.w};
#pragma unroll
        for (int a = 0; a < 8; ++a)
#pragma unroll
          for (int b2 = 0; b2 < 8; ++b2) acc[a][b2] = fmaf(wv[a], xv[b2], acc[a][b2]);
      }
    }

    // butterfly reduce-scatter over es lane-bits 8,16,32
    float r1[4][8];
#pragma unroll
    for (int a = 0; a < 4; ++a)
#pragma unroll
      for (int b2 = 0; b2 < 8; ++b2) {
        float sendv = hi1 ? acc[a][b2] : acc[a + 4][b2];
        float keepv = hi1 ? acc[a + 4][b2] : acc[a][b2];
        r1[a][b2] = keepv + __shfl_xor(sendv, 8, 64);
      }
    float r2[4][4];
#pragma unroll
    for (int a = 0; a < 4; ++a)
#pragma unroll
      for (int b2 = 0; b2 < 4; ++b2) {
        float sendv = hi2 ? r1[a][b2] : r1[a][b2 + 4];
        float keepv = hi2 ? r1[a][b2 + 4] : r1[a][b2];
        r2[a][b2] = keepv + __shfl_xor(sendv, 16, 64);
      }
    float r3[2][4];
#pragma unroll
    for (int a = 0; a < 2; ++a)
#pragma unroll
      for (int b2 = 0; b2 < 4; ++b2) {
        float sendv = hi3 ? r2[a][b2] : r2[a + 2][b2];
        float keepv = hi3 ? r2[a + 2][b2] : r2[a][b2];
        r3[a][b2] = keepv + __shfl_xor(sendv, 32, 64);
      }
    const size_t base = (size_t)(ut * 4 + ct) * (TPH * 1024) + (size_t)cc * 32;
#pragma unroll
    for (int a = 0; a < 2; ++a)
#pragma unroll
      for (int b2 = 0; b2 < 4; ++b2) {
        int tau = rt * 8 + bb + b2;
        if (t0 + tau < sl)
          dst[base + (size_t)tau * 1024 + (jt * 8 + ab1 + ab2 + a)] = r3[a][b2];
      }
  }
}

// ---------------- LSTM recurrent phase (cooperative, 256 WGs) — r5-proven config ----------------
// Fence-free h exchange: write-through agent stores + L2-bypass agent loads.
__global__ __launch_bounds__(BLK, 1) void lstm_phase(
    int phase, const int* __restrict__ seq_lens, const float* __restrict__ Wh_f,
    const float* __restrict__ Wh_b, const float* __restrict__ b_f,
    const float* __restrict__ b_b, const float* __restrict__ W_out,
    const float* __restrict__ xp, const float* __restrict__ xp2,
    float* __restrict__ hbuf, float* __restrict__ cbuf,
    unsigned long long* __restrict__ featsFix, unsigned* __restrict__ bar) {
  extern __shared__ float sm[];
  float* wS = sm + LW_OFF;
  float* hS = sm + LH_OFF;
  float* gS = sm + LG_OFF;
  float* xpS = sm + LXP_OFF;
  float* hlS = sm + LHL_OFF;
  float* cstS = sm + LCS_OFF;
  float* biasS = sm + LBI_OFF;
  float* woutS = sm + LWO_OFF;
  int* slS = (int*)(sm + LSL_OFF);
  int* mslS = (int*)(sm + LMX_OFF);

  const int tid = threadIdx.x;
  const int bid = blockIdx.x;
  const int ut = bid & 63, ct = bid >> 6;
  const int u0 = ut * 8, ch0 = ct * 32, dir = ct >> 1;
  const float* Wh = dir ? Wh_b : Wh_f;
  const float* bb = dir ? b_b : b_f;

  if (tid < 32) slS[tid] = seq_lens[((ct & 1) << 5) + tid];
  __syncthreads();
  if (tid == 0) {
    int m = 0;
    for (int c = 0; c < 32; ++c) m = max(m, slS[c]);
    *mslS = m;
  }
  __syncthreads();
  const int gmax = *mslS;
  const int t0 = phase * TPH;
  if (t0 >= gmax) return;  // group-uniform exit

  for (int j = 0; j < 32; ++j) {
    int row = (j >> 3) * 512 + u0 + (j & 7);
    for (int ee = tid; ee < 512; ee += BLK)
      wS[ee * 32 + ((((j >> 2) ^ (ee & 7)) << 2) | (j & 3))] = Wh[row * 512 + ee];
  }
  if (tid < 96) woutS[tid] = W_out[(tid >> 3) * 1024 + dir * 512 + u0 + (tid & 7)];
  if (tid < 32) biasS[tid] = bb[(tid >> 3) * 512 + u0 + (tid & 7)];
  cstS[tid] = cbuf[bid * 256 + tid];
  __syncthreads();

  const int lane = tid & 63, w = tid >> 6;
  const int tp = lane & 15, jt = tp & 3, ct2 = tp >> 2;
  const int es = w * 4 + (lane >> 4);
  const int esw = es & 7;
  const int nst = min(TPH, gmax - t0);

  const float* wpA = wS + es * 32 + (((jt * 2) ^ esw) << 2);
  const float* wpB = wS + es * 32 + (((jt * 2 + 1) ^ esw) << 2);
  const float* hpA = hS + es * 32 + (((ct2 * 2) ^ esw) << 2);
  const float* hpB = hS + es * 32 + (((ct2 * 2 + 1) ^ esw) << 2);

  const size_t xb0 = (size_t)(ut * 4 + ct) * TPH * 1024;
  float4 xr = *(const float4*)(xp + xb0 + tid * 4);
  float4 xr2 = *(const float4*)(xp2 + xb0 + tid * 4);

  for (int tl = 0; tl < nst; ++tl) {
    const int t = t0 + tl;
    const float* hcur = hbuf + (t & 1) * 65536;
    float* hnxt = hbuf + ((t + 1) & 1) * 65536;

    // ---- wait: h(t) published (flag >= t); no acquire fence needed (bypass loads) ----
    if (tid == 0) {
      while (__hip_atomic_load(&bar[ct * 64], __ATOMIC_RELAXED,
                               __HIP_MEMORY_SCOPE_AGENT) < (unsigned)t) {}
    }
    __syncthreads();

    // [A] stage h slice -> regs (L2-bypass, pipelined) -> LDS (swizzled)
    {
      u64t hq[32];
#pragma unroll
      for (int it = 0; it < 16; ++it) {
        int u = it * 32 + (tid >> 3), q = tid & 7;
        const u64t* p = (const u64t*)(hcur + u * 128 + ch0 + q * 4);
        hq[2 * it] = __hip_atomic_load(p, __ATOMIC_RELAXED, __HIP_MEMORY_SCOPE_AGENT);
        hq[2 * it + 1] =
            __hip_atomic_load(p + 1, __ATOMIC_RELAXED, __HIP_MEMORY_SCOPE_AGENT);
      }
#pragma unroll
      for (int it = 0; it < 16; ++it) {
        int u = it * 32 + (tid >> 3), q = tid & 7;
        union { u64t q2[2]; float4 v; } uu2;
        uu2.q2[0] = hq[2 * it];
        uu2.q2[1] = hq[2 * it + 1];
        *(float4*)(hS + u * 32 + ((q ^ (u & 7)) << 2)) = uu2.v;
      }
    }
    {
      int c = tid >> 3, j4 = tid & 7;
      float* d = xpS + c * 33 + j4 * 4;
      d[0] = xr.x + xr2.x;
      d[1] = xr.y + xr2.y;
      d[2] = xr.z + xr2.z;
      d[3] = xr.w + xr2.w;
    }
    if (tl + 1 < nst) {
      xr = *(const float4*)(xp + xb0 + (size_t)(tl + 1) * 1024 + tid * 4);
      xr2 = *(const float4*)(xp2 + xb0 + (size_t)(tl + 1) * 1024 + tid * 4);
    }
    __syncthreads();

    // [B] 32x32x512 matmul: 8x8 register tile
    float acc[8][8];
#pragma unroll
    for (int a = 0; a < 8; ++a)
#pragma unroll
      for (int b2 = 0; b2 < 8; ++b2) acc[a][b2] = 0.f;
    for (int io = 0; io < 4; ++io) {
#pragma unroll
      for (int ii = 0; ii < 8; ++ii) {
        const int off = (io * 8 + ii) * 512;
        const float4 w0 = *(const float4*)(wpA + off);
        const float4 w1 = *(const float4*)(wpB + off);
        const float4 x0 = *(const float4*)(hpA + off);
        const float4 x1 = *(const float4*)(hpB + off);
        float wv[8] = {w0.x, w0.y, w0.z, w0.w, w1.x, w1.y, w1.z, w1.w};
        float xv[8] = {x0.x, x0.y, x0.z, x0.w, x1.x, x1.y, x1.z, x1.w};
#pragma unroll
        for (int a = 0; a < 8; ++a)
#pragma unroll
          for (int b2 = 0; b2 < 8; ++b2) acc[a][b2] = fmaf(wv[a], xv[b2], acc[a][b2]);
      }
    }

    // in-wave butterfly reduce-scatter over es lane-bits 16,32
    const bool hi1 = (lane & 16) != 0;
    float r1[4][8];
#pragma unroll
    for (int a = 0; a < 4; ++a)
#pragma unroll
      for (int b2 = 0; b2 < 8; ++b2) {
        float sendv = hi1 ? acc[a][b2] : acc[a + 4][b2];
        float keepv = hi1 ? acc[a + 4][b2] : acc[a][b2];
        r1[a][b2] = keepv + __shfl_xor(sendv, 16, 64);
      }
    const bool hi2 = (lane & 32) != 0;
    float r2[4][4];
#pragma unroll
    for (int a = 0; a < 4; ++a)
#pragma unroll
      for (int b2 = 0; b2 < 4; ++b2) {
        float sendv = hi2 ? r1[a][b2] : r1[a][b2 + 4];
        float keepv = hi2 ? r1[a][b2 + 4] : r1[a][b2];
        r2[a][b2] = keepv + __shfl_xor(sendv, 32, 64);
      }
    const int ab = hi1 ? 4 : 0, bbs = hi2 ? 4 : 0;
#pragma unroll
    for (int a = 0; a < 4; ++a) {
      float4 v = make_float4(r2[a][0], r2[a][1], r2[a][2], r2[a][3]);
      *(float4*)(gS + w * 1024 + (jt * 8 + ab + a) * 32 + ct2 * 8 + bbs) = v;
    }
    __syncthreads();

    // [C] epilogue: combine 4 wave-partials + xp + bias -> gates -> c,h
    {
      const int uu = tid >> 5, c = tid & 31;
      const int slc = slS[c];
      float s0 = 0.f, s1 = 0.f, s2 = 0.f, s3 = 0.f;
#pragma unroll
      for (int w2 = 0; w2 < 4; ++w2) {
        const float* gp = gS + w2 * 1024 + uu * 32 + c;
        s0 += gp[0];
        s1 += gp[256];
        s2 += gp[512];
        s3 += gp[768];
      }
      const bool xvalid = (t < slc);
      float x0 = xvalid ? xpS[c * 33 + uu] : 0.f;
      float x1 = xvalid ? xpS[c * 33 + 8 + uu] : 0.f;
      float x2 = xvalid ? xpS[c * 33 + 16 + uu] : 0.f;
      float x3 = xvalid ? xpS[c * 33 + 24 + uu] : 0.f;
      float iv = s0 + x0 + biasS[uu];
      float fv = s1 + x1 + biasS[8 + uu];
      float gv = s2 + x2 + biasS[16 + uu];
      float ov = s3 + x3 + biasS[24 + uu];
      float cn = sigm(fv) * cstS[uu * 32 + c] + sigm(iv) * tanhf(gv);
      float hn = sigm(ov) * tanhf(cn);
      cstS[uu * 32 + c] = cn;
      // write-through agent store: publishes h without wbl2
      __hip_atomic_store(&hnxt[(u0 + uu) * 128 + ch0 + c], hn, __ATOMIC_RELAXED,
                         __HIP_MEMORY_SCOPE_AGENT);
      hlS[uu * 32 + c] = hn;
    }
    // drain this wave's h stores to the coherence point, then block-wide sync
    asm volatile("s_waitcnt vmcnt(0)" ::: "memory");
    __syncthreads();

    // ---- arrive: counter RMW + broadcast flag (relaxed agent; no release fence) ----
    if (tid == 0) {
      unsigned o = __hip_atomic_fetch_add(&bar[ct * 64 + 16], 1u, __ATOMIC_RELAXED,
                                          __HIP_MEMORY_SCOPE_AGENT);
      if (o == (unsigned)(t + 1) * 64u - 1u)
        __hip_atomic_store(&bar[ct * 64], (unsigned)(t + 1), __ATOMIC_RELAXED,
                           __HIP_MEMORY_SCOPE_AGENT);
    }

    // feats partial (fixed-point atomics) — issued after arrive, drains during next poll
    for (int base = 0; base < 384; base += 256) {
      int idx = base + tid;
      if (idx < 384) {
        int c = idx / 12, k = idx % 12;
        int sl = slS[c];
        if (t < sl) {
          float pacc = 0.f;
#pragma unroll
          for (int uu = 0; uu < 8; ++uu) pacc += hlS[uu * 32 + c] * woutS[k * 8 + uu];
          int tt = dir ? (sl - 1 - t) : t;
          double y = (double)pacc * FIX_SCALE;
          long long q = (long long)(y + (y >= 0.0 ? 0.5 : -0.5));
          atomicAdd(&featsFix[((size_t)(((ct & 1) << 5) + c) * 512 + tt) * 12 + k],
                    (unsigned long long)q);
        }
      }
    }
  }
  cbuf[bid * 256 + tid] = cstS[tid];
}

// ---------------- viterbi: 64 blocks (one b each), fv replicated via shfl ----------------
__global__ __launch_bounds__(64) void viterbi2(
    const int* __restrict__ seq_lens, const float* __restrict__ b_out,
    const float* __restrict__ transitions,
    const unsigned long long* __restrict__ featsFix,
    unsigned char* __restrict__ bps, float* __restrict__ out) {
  __shared__ unsigned char tagB[512];
  const int b = blockIdx.x;
  const int lane = threadIdx.x;
  const int k = lane < 12 ? lane : 0;
  const int sl = seq_lens[b];
  float trow[12];
#pragma unroll
  for (int p = 0; p < 12; ++p) trow[p] = transitions[k * 12 + p];
  const float bo = b_out[k];
  float fvv[12];
#pragma unroll
  for (int p = 0; p < 12; ++p) fvv[p] = (p == START_TAG) ? 0.f : -10000.f;
  const unsigned long long* fbase = featsFix + (size_t)b * 512 * 12;
  long long fx = (long long)fbase[k];
  for (int t = 0; t < TSEQ; ++t) {
    float best = fvv[0] + trow[0];
    int arg = 0;
#pragma unroll
    for (int p = 1; p < 12; ++p) {
      float v = fvv[p] + trow[p];
      if (v > best) { best = v; arg = p; }
    }
    float feat = (float)((double)fx * FIX_INV) + bo;
    if (t + 1 < TSEQ) fx = (long long)fbase[(t + 1) * 12 + k];
    const bool m = t < sl;
    float nv = m ? (best + feat) : fvv[k];
    int bpv = m ? arg : k;
    if (lane < 12) bps[((size_t)t * 64 + b) * 12 + lane] = (unsigned char)bpv;
#pragma unroll
    for (int p = 0; p < 12; ++p) fvv[p] = __shfl(nv, p, 64);
  }
  __syncthreads();
  if (lane == 0) {
    float best = fvv[0] + transitions[STOP_TAG * 12 + 0];
    int arg = 0;
    for (int kk = 1; kk < 12; ++kk) {
      float v = fvv[kk] + transitions[STOP_TAG * 12 + kk];
      if (v > best) { best = v; arg = kk; }
    }
    out[b] = best;
    int tag = arg;
    const uint32_t* rowp = (const uint32_t*)bps;
    uint32_t r0, r1, r2;
    {
      size_t off = ((size_t)511 * 64 + b) * 3;
      r0 = rowp[off]; r1 = rowp[off + 1]; r2 = rowp[off + 2];
    }
    for (int t = 511; t >= 0; --t) {
      uint32_t n0 = 0, n1 = 0, n2 = 0;
      if (t > 0) {
        size_t off = ((size_t)(t - 1) * 64 + b) * 3;
        n0 = rowp[off]; n1 = rowp[off + 1]; n2 = rowp[off + 2];
      }
      tagB[t] = (unsigned char)tag;
      uint32_t sel = (tag < 4) ? (r0 >> (tag * 8))
                   : (tag < 8) ? (r1 >> ((tag - 4) * 8))
                               : (r2 >> ((tag - 8) * 8));
      tag = (int)(sel & 0xffu);
      r0 = n0; r1 = n1; r2 = n2;
    }
  }
  __syncthreads();
  for (int t = lane; t < 512; t += 64) out[64 + (size_t)b * 512 + t] = (float)tagB[t];
}

extern "C" void kernel_launch(void* const* d_in, const int* in_sizes, int n_in,
                              void* d_out, int out_size, void* d_ws, size_t ws_size,
                              hipStream_t stream) {
  (void)in_sizes; (void)n_in; (void)out_size; (void)ws_size;
  const int* sentence = (const int*)d_in[0];
  const int* seq_lens = (const int*)d_in[1];
  const float* embed = (const float*)d_in[2];
  const float* Wi_f = (const float*)d_in[3];
  const float* Wh_f = (const float*)d_in[4];
  const float* b_f = (const float*)d_in[5];
  const float* Wi_b = (const float*)d_in[6];
  const float* Wh_b = (const float*)d_in[7];
  const float* b_b = (const float*)d_in[8];
  const float* h0 = (const float*)d_in[9];
  const float* c0 = (const float*)d_in[10];
  const float* W_out = (const float*)d_in[11];
  const float* b_out = (const float*)d_in[12];
  const float* trans = (const float*)d_in[13];

  char* ws = (char*)d_ws;
  unsigned* bar = (unsigned*)ws;
  unsigned long long* featsFix = (unsigned long long*)(ws + FEATS_OFF);
  float* hbuf = (float*)(ws + HBUF_OFF);
  float* cbuf = (float*)(ws + CBUF_OFF);
  unsigned char* bps = (unsigned char*)(ws + BPS_OFF);
  float* xpw = (float*)(ws + XP_OFF);
  float* xpw2 = (float*)(ws + XP2_OFF);

  hipMemsetAsync(d_ws, 0, FEATS_OFF + FEATS_BYTES, stream);  // bar + featsFix

  hipFuncSetAttribute((const void*)lstm_phase,
                      hipFuncAttributeMaxDynamicSharedMemorySize, LSTM_SMEM_BYTES);
  hipFuncSetAttribute((const void*)pre_gemm,
                      hipFuncAttributeMaxDynamicSharedMemorySize, PRE_SMEM_BYTES);

  init_state<<<dim3(512), dim3(256), 0, stream>>>(h0, c0, hbuf, cbuf);

  for (int p = 0; p < NPH; ++p) {
    pre_gemm<<<dim3(256, 8), dim3(BLK), PRE_SMEM_BYTES, stream>>>(
        p, sentence, seq_lens, embed, Wi_f, Wi_b, xpw, xpw2);
    int pv = p;
    void* kargs[] = {(void*)&pv,   (void*)&seq_lens, (void*)&Wh_f,  (void*)&Wh_b,
                     (void*)&b_f,  (void*)&b_b,      (void*)&W_out, (void*)&xpw,
                     (void*)&xpw2, (void*)&hbuf,     (void*)&cbuf,  (void*)&featsFix,
                     (void*)&bar};
    hipLaunchCooperativeKernel((const void*)lstm_phase, dim3(NWG), dim3(BLK), kargs,
                               LSTM_SMEM_BYTES, stream);
  }
  viterbi2<<<dim3(64), dim3(64), 0, stream>>>(seq_lens, b_out, trans, featsFix, bps,
                                              (float*)d_out);
}

// Round 8
// 5790.657 us; speedup vs baseline: 1.2444x; 1.0584x over previous
//
#include <hip/hip_runtime.h>
#include <stdint.h>

// ---------------- problem constants ----------------
#define BSZ 64
#define TSEQ 512
#define KTAG 12
#define START_TAG 10
#define STOP_TAG 11

#define TPH 64   // timesteps per phase
#define NPH 8    // phases (TPH*NPH == TSEQ)
#define NWG 256
#define BLK 256

#define FIX_SCALE 4294967296.0
#define FIX_INV 2.3283064365386963e-10

typedef unsigned long long u64t;
typedef __attribute__((ext_vector_type(8))) short bf16x8;
typedef __attribute__((ext_vector_type(4))) float f32x4;

// ---------------- workspace layout (bytes) ----------------
// bar: per ct (4 groups): flag at [ct*64], counter at [ct*64+16]
#define BAR_BYTES 4096
#define FEATS_OFF BAR_BYTES
#define FEATS_BYTES (BSZ * TSEQ * KTAG * 8)         // u64 fixed-point
#define HBUF_OFF (FEATS_OFF + FEATS_BYTES)
#define HBUF_BYTES (2 * 128 * 512 * 4)              // ping-pong h, layout [ch][u] !
#define CBUF_OFF (HBUF_OFF + HBUF_BYTES)
#define CBUF_BYTES (NWG * 256 * 4)
#define BPS_OFF (CBUF_OFF + CBUF_BYTES)
#define BPS_BYTES (TSEQ * BSZ * KTAG)
#define XP_OFF (BPS_OFF + BPS_BYTES)
#define XP_BYTES (64 * 4 * TPH * 32 * 32 * 4)       // K-half 0
#define XP2_OFF (XP_OFF + XP_BYTES)
#define XP2_BYTES XP_BYTES                          // K-half 1

// ---------------- LSTM kernel LDS (byte offsets) ----------------
// bf16 arrays [32 rows][512 e], swizzled: byte = row*1024 + ((2e) ^ ((row&15)<<4))
#define WAH_OFF 0           // Wh hi  (32 KB)
#define WAL_OFF 32768       // Wh lo
#define HBH_OFF 65536       // h^T hi (32 KB)
#define HBL_OFF 98304       // h^T lo
#define GS_OFF 131072       // 4 waves x [32][36] f32 = 18432 B
#define XPS_OFF 149504      // [32][36] f32 = 4608 B
#define HLS_OFF 154112      // 256 f32 (tid = c*8+uu)
#define CST_OFF 155136      // 256 f32
#define BIAS_OFF 156160     // 32 f32
#define WOUT_OFF 156288     // 96 f32
#define SL_OFF 156672       // 32 int
#define MSL_OFF 156800      // 1 int
#define LSTM_SMEM_BYTES 156804

// ---------------- pre-GEMM kernel LDS (unchanged, float offsets) ----------------
#define PW_OFF 0
#define PE_OFF 8192
#define PT_OFF 16384
#define PRE_SMEM_FLOATS 16448
#define PRE_SMEM_BYTES (PRE_SMEM_FLOATS * 4)

__device__ __forceinline__ float sigm(float x) { return 1.f / (1.f + expf(-x)); }

__device__ __forceinline__ unsigned cvtpk(float a, float b) {
  unsigned r;
  asm("v_cvt_pk_bf16_f32 %0, %1, %2" : "=v"(r) : "v"(a), "v"(b));
  return r;  // lo16 = bf16(a), hi16 = bf16(b)
}
// split pair (a,b) -> packed hi bf16s + packed lo (residual) bf16s
__device__ __forceinline__ void split2(float a, float b, unsigned& hi, unsigned& lo) {
  hi = cvtpk(a, b);
  float ha = __uint_as_float(hi << 16);
  float hb = __uint_as_float(hi & 0xFFFF0000u);
  lo = cvtpk(a - ha, b - hb);
}

// ---------------- init: h0 -> hbufT slot 0 ([ch][u]), c0 -> cbuf (tid = c*8+uu) ----------------
__global__ void init_state(const float* __restrict__ h0, const float* __restrict__ c0,
                           float* __restrict__ hbuf, float* __restrict__ cbuf) {
  int i = blockIdx.x * 256 + threadIdx.x;
  if (i < 65536) {
    int ch = i >> 9, u = i & 511;
    int ct = ch >> 5, c = ch & 31;
    int dir = ct >> 1, b = ((ct & 1) << 5) + c;
    hbuf[i] = h0[(dir * 64 + b) * 512 + u];
  } else {
    int j = i - 65536;
    int wg = j >> 8, r = j & 255;
    int ct = wg >> 6, ut = wg & 63;
    int c = r >> 3, uu = r & 7;
    int dir = ct >> 1, b = ((ct & 1) << 5) + c;
    cbuf[j] = c0[(dir * 64 + b) * 512 + ut * 8 + uu];
  }
}

// ---------------- pre-GEMM: K-split (kh in {0,1}), one WG = (kh,dir,ut) x 8 b rows ----------------
__global__ __launch_bounds__(256, 2) void pre_gemm(
    int phase, const int* __restrict__ sentence, const int* __restrict__ seq_lens,
    const float* __restrict__ embed, const float* __restrict__ Wi_f,
    const float* __restrict__ Wi_b, float* __restrict__ xp, float* __restrict__ xp2) {
  extern __shared__ float sm[];
  float* wiS = sm + PW_OFF;
  float* embS = sm + PE_OFF;
  int* tokS = (int*)(sm + PT_OFF);

  const int tid = threadIdx.x;
  const int bx = blockIdx.x;               // 256: kh*128 + dirut
  const int kh = bx >> 7;
  const int dirut = bx & 127;
  const int dir = dirut >> 6, ut = dirut & 63;
  const int yo = blockIdx.y;
  const int t0 = phase * TPH;
  if (t0 >= seq_lens[yo * 8]) return;
  const int u0 = ut * 8;
  const int e0 = kh * 256;
  const float* Wi = dir ? Wi_b : Wi_f;
  float* dst = kh ? xp2 : xp;

  for (int j = 0; j < 32; ++j) {
    int row = (j >> 3) * 512 + u0 + (j & 7);
    int ee = tid;
    wiS[ee * 32 + ((((j >> 2) ^ (ee & 7)) << 2) | (j & 3))] = Wi[row * 512 + e0 + ee];
  }

  const int lane = tid & 63, w = tid >> 6;
  const int es = lane >> 3, tl8 = lane & 7;
  const int tile = w * 8 + tl8;
  const int jt = tile & 3, rt = tile >> 2;
  const int rr = tid & 63, seg = tid >> 6;
  const int rq = rr >> 2, rl = rr & 3;
  const float* wp0b = wiS + (((jt * 2) ^ es) << 2) + es * 32;
  const float* wp1b = wiS + (((jt * 2 + 1) ^ es) << 2) + es * 32;
  const float* ep0 = embS + es * 64 + (((rt * 2) ^ es) << 2);
  const float* ep1 = embS + es * 64 + (((rt * 2 + 1) ^ es) << 2);
  const bool hi1 = (lane & 8) != 0;
  const bool hi2 = (lane & 16) != 0;
  const bool hi3 = (lane & 32) != 0;
  const int ab1 = hi1 ? 4 : 0, bb = hi2 ? 4 : 0, ab2 = hi3 ? 2 : 0;

  for (int ib = 0; ib < 8; ++ib) {
    const int b = yo * 8 + ib;
    const int sl = seq_lens[b];
    if (t0 >= sl) break;
    const int ct = dir * 2 + (b >> 5);
    const int cc = b & 31;

    __syncthreads();
    if (tid < 64) {
      int tg = t0 + tid;
      int pos = dir ? (sl - 1 - tg) : tg;
      pos = min(max(pos, 0), 511);
      tokS[tid] = sentence[b * 512 + pos];
    }
    __syncthreads();

    const int mytok = tokS[rr];
    float4 vb[2][8];
    {
      const float* src = embed + (size_t)mytok * 512 + e0 + seg * 32;
#pragma unroll
      for (int q = 0; q < 8; ++q) vb[0][q] = *(const float4*)(src + q * 4);
    }
    float acc[8][8];
#pragma unroll
    for (int a = 0; a < 8; ++a)
#pragma unroll
      for (int b2 = 0; b2 < 8; ++b2) acc[a][b2] = 0.f;

#pragma unroll
    for (int kk = 0; kk < 2; ++kk) {
      if (kk) __syncthreads();
#pragma unroll
      for (int q = 0; q < 8; ++q) {
        const int el = seg * 32 + q * 4;
        const float4 v = vb[kk & 1][q];
        embS[(el + 0) * 64 + (((rq ^ ((el + 0) & 7)) << 2) | rl)] = v.x;
        embS[(el + 1) * 64 + (((rq ^ ((el + 1) & 7)) << 2) | rl)] = v.y;
        embS[(el + 2) * 64 + (((rq ^ ((el + 2) & 7)) << 2) | rl)] = v.z;
        embS[(el + 3) * 64 + (((rq ^ ((el + 3) & 7)) << 2) | rl)] = v.w;
      }
      if (kk < 1) {
        const float* src = embed + (size_t)mytok * 512 + e0 + 128 + seg * 32;
#pragma unroll
        for (int q = 0; q < 8; ++q) vb[(kk + 1) & 1][q] = *(const float4*)(src + q * 4);
      }
      __syncthreads();
      const float* wp0 = wp0b + kk * 128 * 32;
      const float* wp1 = wp1b + kk * 128 * 32;
#pragma unroll
      for (int i = 0; i < 16; ++i) {
        const float4 w0 = *(const float4*)(wp0 + i * 256);
        const float4 w1 = *(const float4*)(wp1 + i * 256);
        const float4 x0 = *(const float4*)(ep0 + i * 512);
        const float4 x1 = *(const float4*)(ep1 + i * 512);
        float wv[8] = {w0.x, w0.y, w0.z, w0.w, w1.x, w1.y, w1.z, w1.w};
        float xv[8] = {x0.x, x0.y, x0.z, x0.w, x1.x, x1.y, x1.z, x1.w};
#pragma unroll
        for (int a = 0; a < 8; ++a)
#pragma unroll
          for (int b2 = 0; b2 < 8; ++b2) acc[a][b2] = fmaf(wv[a], xv[b2], acc[a][b2]);
      }
    }

    float r1[4][8];
#pragma unroll
    for (int a = 0; a < 4; ++a)
#pragma unroll
      for (int b2 = 0; b2 < 8; ++b2) {
        float sendv = hi1 ? acc[a][b2] : acc[a + 4][b2];
        float keepv = hi1 ? acc[a + 4][b2] : acc[a][b2];
        r1[a][b2] = keepv + __shfl_xor(sendv, 8, 64);
      }
    float r2[4][4];
#pragma unroll
    for (int a = 0; a < 4; ++a)
#pragma unroll
      for (int b2 = 0; b2 < 4; ++b2) {
        float sendv = hi2 ? r1[a][b2] : r1[a][b2 + 4];
        float keepv = hi2 ? r1[a][b2 + 4] : r1[a][b2];
        r2[a][b2] = keepv + __shfl_xor(sendv, 16, 64);
      }
    float r3[2][4];
#pragma unroll
    for (int a = 0; a < 2; ++a)
#pragma unroll
      for (int b2 = 0; b2 < 4; ++b2) {
        float sendv = hi3 ? r2[a][b2] : r2[a + 2][b2];
        float keepv = hi3 ? r2[a + 2][b2] : r2[a][b2];
        r3[a][b2] = keepv + __shfl_xor(sendv, 32, 64);
      }
    const size_t base = (size_t)(ut * 4 + ct) * (TPH * 1024) + (size_t)cc * 32;
#pragma unroll
    for (int a = 0; a < 2; ++a)
#pragma unroll
      for (int b2 = 0; b2 < 4; ++b2) {
        int tau = rt * 8 + bb + b2;
        if (t0 + tau < sl)
          dst[base + (size_t)tau * 1024 + (jt * 8 + ab1 + ab2 + a)] = r3[a][b2];
      }
  }
}

// ---------------- LSTM recurrent phase: split-bf16 MFMA core ----------------
// h@Wh.T via mfma_f32_16x16x32_bf16, 3-product hi/lo split. Fence-free h exchange
// (r5 protocol). hbuf layout [ch][u] so h^T stages to LDS without transpose.
__global__ __launch_bounds__(BLK, 1) void lstm_phase(
    int phase, const int* __restrict__ seq_lens, const float* __restrict__ Wh_f,
    const float* __restrict__ Wh_b, const float* __restrict__ b_f,
    const float* __restrict__ b_b, const float* __restrict__ W_out,
    const float* __restrict__ xp, const float* __restrict__ xp2,
    float* __restrict__ hbuf, float* __restrict__ cbuf,
    unsigned long long* __restrict__ featsFix, unsigned* __restrict__ bar) {
  extern __shared__ char smc[];
  char* WAH = smc + WAH_OFF;
  char* WAL = smc + WAL_OFF;
  char* HBH = smc + HBH_OFF;
  char* HBL = smc + HBL_OFF;
  float* gS = (float*)(smc + GS_OFF);
  float* xpS = (float*)(smc + XPS_OFF);
  float* hlS = (float*)(smc + HLS_OFF);
  float* cstS = (float*)(smc + CST_OFF);
  float* biasS = (float*)(smc + BIAS_OFF);
  float* woutS = (float*)(smc + WOUT_OFF);
  int* slS = (int*)(smc + SL_OFF);
  int* mslS = (int*)(smc + MSL_OFF);

  const int tid = threadIdx.x;
  const int bid = blockIdx.x;
  const int ut = bid & 63, ct = bid >> 6;
  const int u0 = ut * 8, ch0 = ct * 32, dir = ct >> 1;
  const float* Wh = dir ? Wh_b : Wh_f;
  const float* bb = dir ? b_b : b_f;

  if (tid < 32) slS[tid] = seq_lens[((ct & 1) << 5) + tid];
  __syncthreads();
  if (tid == 0) {
    int m = 0;
    for (int c = 0; c < 32; ++c) m = max(m, slS[c]);
    *mslS = m;
  }
  __syncthreads();
  const int gmax = *mslS;
  const int t0 = phase * TPH;
  if (t0 >= gmax) return;

  // ---- stage Wh slice as bf16 hi/lo (once per phase) ----
  {
    const int jj = tid & 31, sgw = tid >> 5;
    const int row = (jj >> 3) * 512 + u0 + (jj & 7);
    const unsigned swz = (unsigned)((jj & 15) << 4);
    for (int it = 0; it < 8; ++it) {
      const int e = it * 64 + sgw * 8;
      float4 v0 = *(const float4*)(Wh + row * 512 + e);
      float4 v1 = *(const float4*)(Wh + row * 512 + e + 4);
      unsigned h0, h1, h2, h3, l0, l1, l2, l3;
      split2(v0.x, v0.y, h0, l0);
      split2(v0.z, v0.w, h1, l1);
      split2(v1.x, v1.y, h2, l2);
      split2(v1.z, v1.w, h3, l3);
      const unsigned off = (unsigned)(jj * 1024) + (((unsigned)(e * 2)) ^ swz);
      *(uint4*)(WAH + off) = make_uint4(h0, h1, h2, h3);
      *(uint4*)(WAL + off) = make_uint4(l0, l1, l2, l3);
    }
  }
  if (tid < 96) woutS[tid] = W_out[(tid >> 3) * 1024 + dir * 512 + u0 + (tid & 7)];
  if (tid < 32) biasS[tid] = bb[(tid >> 3) * 512 + u0 + (tid & 7)];
  cstS[tid] = cbuf[bid * 256 + tid];   // tid = c*8+uu
  __syncthreads();

  const int l = tid & 63, w = tid >> 6;
  const int lr = l & 15;
  const int ef = (l >> 4) * 8;
  const int cc = tid & 31, sg = tid >> 5;     // h-staging mapping
  const int cE = tid >> 3, uuE = tid & 7;     // epilogue mapping
  const int nst = min(TPH, gmax - t0);

  const size_t xb0 = (size_t)(ut * 4 + ct) * TPH * 1024;
  float4 xr = *(const float4*)(xp + xb0 + tid * 4);
  float4 xr2 = *(const float4*)(xp2 + xb0 + tid * 4);

  for (int tl = 0; tl < nst; ++tl) {
    const int t = t0 + tl;
    const float* hcur = hbuf + (t & 1) * 65536;
    float* hnxt = hbuf + ((t + 1) & 1) * 65536;

    // ---- wait: h(t) published ----
    if (tid == 0) {
      while (__hip_atomic_load(&bar[ct * 64], __ATOMIC_RELAXED,
                               __HIP_MEMORY_SCOPE_AGENT) < (unsigned)t) {}
    }
    __syncthreads();

    // [A] stage h^T slice -> regs (L2-bypass) -> bf16 hi/lo LDS (no transpose needed)
    {
      u64t hq[32];
      const u64t* hrow = (const u64t*)(hcur + (ch0 + cc) * 512);
#pragma unroll
      for (int it = 0; it < 8; ++it) {
        const u64t* p = hrow + ((it * 64 + sg * 8) >> 1);
        hq[4 * it + 0] = __hip_atomic_load(p + 0, __ATOMIC_RELAXED, __HIP_MEMORY_SCOPE_AGENT);
        hq[4 * it + 1] = __hip_atomic_load(p + 1, __ATOMIC_RELAXED, __HIP_MEMORY_SCOPE_AGENT);
        hq[4 * it + 2] = __hip_atomic_load(p + 2, __ATOMIC_RELAXED, __HIP_MEMORY_SCOPE_AGENT);
        hq[4 * it + 3] = __hip_atomic_load(p + 3, __ATOMIC_RELAXED, __HIP_MEMORY_SCOPE_AGENT);
      }
      const unsigned swz = (unsigned)((cc & 15) << 4);
#pragma unroll
      for (int it = 0; it < 8; ++it) {
        const int e = it * 64 + sg * 8;
        unsigned hw[4], lw[4];
#pragma unroll
        for (int p2 = 0; p2 < 4; ++p2) {
          u64t q2 = hq[4 * it + p2];
          float fa = __uint_as_float((unsigned)(q2 & 0xFFFFFFFFu));
          float fb = __uint_as_float((unsigned)(q2 >> 32));
          split2(fa, fb, hw[p2], lw[p2]);
        }
        const unsigned off = (unsigned)(cc * 1024) + (((unsigned)(e * 2)) ^ swz);
        *(uint4*)(HBH + off) = make_uint4(hw[0], hw[1], hw[2], hw[3]);
        *(uint4*)(HBL + off) = make_uint4(lw[0], lw[1], lw[2], lw[3]);
      }
    }
    {
      float* d = xpS + cE * 36 + uuE * 4;
      d[0] = xr.x + xr2.x; d[1] = xr.y + xr2.y;
      d[2] = xr.z + xr2.z; d[3] = xr.w + xr2.w;
    }
    if (tl + 1 < nst) {
      xr = *(const float4*)(xp + xb0 + (size_t)(tl + 1) * 1024 + tid * 4);
      xr2 = *(const float4*)(xp2 + xb0 + (size_t)(tl + 1) * 1024 + tid * 4);
    }
    __syncthreads();

    // [B] 32x32x512 via MFMA: wave w = K-quarter, 4 quadrants, 3-product split
    f32x4 acc00 = {0.f, 0.f, 0.f, 0.f}, acc01 = acc00, acc10 = acc00, acc11 = acc00;
    {
      const unsigned sw = (unsigned)(lr << 4);
      const unsigned r0 = (unsigned)(lr * 1024), r1 = (unsigned)((16 + lr) * 1024);
#pragma unroll
      for (int kc = 0; kc < 4; ++kc) {
        const unsigned eb = (unsigned)((w * 128 + kc * 32 + ef) * 2) ^ sw;
        bf16x8 a0h = *(const bf16x8*)(WAH + r0 + eb);
        bf16x8 a1h = *(const bf16x8*)(WAH + r1 + eb);
        bf16x8 a0l = *(const bf16x8*)(WAL + r0 + eb);
        bf16x8 a1l = *(const bf16x8*)(WAL + r1 + eb);
        bf16x8 b0h = *(const bf16x8*)(HBH + r0 + eb);
        bf16x8 b1h = *(const bf16x8*)(HBH + r1 + eb);
        bf16x8 b0l = *(const bf16x8*)(HBL + r0 + eb);
        bf16x8 b1l = *(const bf16x8*)(HBL + r1 + eb);
        acc00 = __builtin_amdgcn_mfma_f32_16x16x32_bf16(a0h, b0h, acc00, 0, 0, 0);
        acc01 = __builtin_amdgcn_mfma_f32_16x16x32_bf16(a0h, b1h, acc01, 0, 0, 0);
        acc10 = __builtin_amdgcn_mfma_f32_16x16x32_bf16(a1h, b0h, acc10, 0, 0, 0);
        acc11 = __builtin_amdgcn_mfma_f32_16x16x32_bf16(a1h, b1h, acc11, 0, 0, 0);
        acc00 = __builtin_amdgcn_mfma_f32_16x16x32_bf16(a0h, b0l, acc00, 0, 0, 0);
        acc01 = __builtin_amdgcn_mfma_f32_16x16x32_bf16(a0h, b1l, acc01, 0, 0, 0);
        acc10 = __builtin_amdgcn_mfma_f32_16x16x32_bf16(a1h, b0l, acc10, 0, 0, 0);
        acc11 = __builtin_amdgcn_mfma_f32_16x16x32_bf16(a1h, b1l, acc11, 0, 0, 0);
        acc00 = __builtin_amdgcn_mfma_f32_16x16x32_bf16(a0l, b0h, acc00, 0, 0, 0);
        acc01 = __builtin_amdgcn_mfma_f32_16x16x32_bf16(a0l, b1h, acc01, 0, 0, 0);
        acc10 = __builtin_amdgcn_mfma_f32_16x16x32_bf16(a1l, b0h, acc10, 0, 0, 0);
        acc11 = __builtin_amdgcn_mfma_f32_16x16x32_bf16(a1l, b1h, acc11, 0, 0, 0);
      }
    }
    // write wave-partial to gS[w][j][c] (D: col=lane&15, row=(lane>>4)*4+reg)
    {
      float* gw = gS + w * (32 * 36);
      const int gr = (l >> 4) * 4;
#pragma unroll
      for (int rg = 0; rg < 4; ++rg) {
        gw[(gr + rg) * 36 + lr] = acc00[rg];
        gw[(gr + rg) * 36 + 16 + lr] = acc01[rg];
        gw[(16 + gr + rg) * 36 + lr] = acc10[rg];
        gw[(16 + gr + rg) * 36 + 16 + lr] = acc11[rg];
      }
    }
    __syncthreads();

    // [C] epilogue: sum 4 wave-partials + xp + bias -> gates -> c,h
    {
      const int c = cE, uu = uuE;
      const int slc = slS[c];
      float s0 = 0.f, s1 = 0.f, s2 = 0.f, s3 = 0.f;
#pragma unroll
      for (int w2 = 0; w2 < 4; ++w2) {
        const float* gp = gS + w2 * (32 * 36) + uu * 36 + c;
        s0 += gp[0];
        s1 += gp[8 * 36];
        s2 += gp[16 * 36];
        s3 += gp[24 * 36];
      }
      const bool xvalid = (t < slc);
      float x0 = xvalid ? xpS[c * 36 + uu] : 0.f;
      float x1 = xvalid ? xpS[c * 36 + 8 + uu] : 0.f;
      float x2 = xvalid ? xpS[c * 36 + 16 + uu] : 0.f;
      float x3 = xvalid ? xpS[c * 36 + 24 + uu] : 0.f;
      float iv = s0 + x0 + biasS[uu];
      float fv = s1 + x1 + biasS[8 + uu];
      float gv = s2 + x2 + biasS[16 + uu];
      float ov = s3 + x3 + biasS[24 + uu];
      float cn = sigm(fv) * cstS[tid] + sigm(iv) * tanhf(gv);
      float hn = sigm(ov) * tanhf(cn);
      cstS[tid] = cn;
      __hip_atomic_store(&hnxt[(ch0 + c) * 512 + u0 + uu], hn, __ATOMIC_RELAXED,
                         __HIP_MEMORY_SCOPE_AGENT);
      hlS[tid] = hn;
    }
    asm volatile("s_waitcnt vmcnt(0)" ::: "memory");
    __syncthreads();

    // ---- arrive ----
    if (tid == 0) {
      unsigned o = __hip_atomic_fetch_add(&bar[ct * 64 + 16], 1u, __ATOMIC_RELAXED,
                                          __HIP_MEMORY_SCOPE_AGENT);
      if (o == (unsigned)(t + 1) * 64u - 1u)
        __hip_atomic_store(&bar[ct * 64], (unsigned)(t + 1), __ATOMIC_RELAXED,
                           __HIP_MEMORY_SCOPE_AGENT);
    }

    // feats partial (fixed-point atomics) — after arrive, drains during next poll
    for (int base = 0; base < 384; base += 256) {
      int idx = base + tid;
      if (idx < 384) {
        int c = idx / 12, k = idx % 12;
        int sl = slS[c];
        if (t < sl) {
          float pacc = 0.f;
#pragma unroll
          for (int uu = 0; uu < 8; ++uu) pacc += hlS[c * 8 + uu] * woutS[k * 8 + uu];
          int tt = dir ? (sl - 1 - t) : t;
          double y = (double)pacc * FIX_SCALE;
          long long q = (long long)(y + (y >= 0.0 ? 0.5 : -0.5));
          atomicAdd(&featsFix[((size_t)(((ct & 1) << 5) + c) * 512 + tt) * 12 + k],
                    (unsigned long long)q);
        }
      }
    }
  }
  cbuf[bid * 256 + tid] = cstS[tid];
}

// ---------------- viterbi: 64 blocks (one b each) ----------------
__global__ __launch_bounds__(64) void viterbi2(
    const int* __restrict__ seq_lens, const float* __restrict__ b_out,
    const float* __restrict__ transitions,
    const unsigned long long* __restrict__ featsFix,
    unsigned char* __restrict__ bps, float* __restrict__ out) {
  __shared__ unsigned char tagB[512];
  const int b = blockIdx.x;
  const int lane = threadIdx.x;
  const int k = lane < 12 ? lane : 0;
  const int sl = seq_lens[b];
  float trow[12];
#pragma unroll
  for (int p = 0; p < 12; ++p) trow[p] = transitions[k * 12 + p];
  const float bo = b_out[k];
  float fvv[12];
#pragma unroll
  for (int p = 0; p < 12; ++p) fvv[p] = (p == START_TAG) ? 0.f : -10000.f;
  const unsigned long long* fbase = featsFix + (size_t)b * 512 * 12;
  long long fx = (long long)fbase[k];
  for (int t = 0; t < TSEQ; ++t) {
    float best = fvv[0] + trow[0];
    int arg = 0;
#pragma unroll
    for (int p = 1; p < 12; ++p) {
      float v = fvv[p] + trow[p];
      if (v > best) { best = v; arg = p; }
    }
    float feat = (float)((double)fx * FIX_INV) + bo;
    if (t + 1 < TSEQ) fx = (long long)fbase[(t + 1) * 12 + k];
    const bool m = t < sl;
    float nv = m ? (best + feat) : fvv[k];
    int bpv = m ? arg : k;
    if (lane < 12) bps[((size_t)t * 64 + b) * 12 + lane] = (unsigned char)bpv;
#pragma unroll
    for (int p = 0; p < 12; ++p) fvv[p] = __shfl(nv, p, 64);
  }
  __syncthreads();
  if (lane == 0) {
    float best = fvv[0] + transitions[STOP_TAG * 12 + 0];
    int arg = 0;
    for (int kk = 1; kk < 12; ++kk) {
      float v = fvv[kk] + transitions[STOP_TAG * 12 + kk];
      if (v > best) { best = v; arg = kk; }
    }
    out[b] = best;
    int tag = arg;
    const uint32_t* rowp = (const uint32_t*)bps;
    uint32_t r0, r1, r2;
    {
      size_t off = ((size_t)511 * 64 + b) * 3;
      r0 = rowp[off]; r1 = rowp[off + 1]; r2 = rowp[off + 2];
    }
    for (int t = 511; t >= 0; --t) {
      uint32_t n0 = 0, n1 = 0, n2 = 0;
      if (t > 0) {
        size_t off = ((size_t)(t - 1) * 64 + b) * 3;
        n0 = rowp[off]; n1 = rowp[off + 1]; n2 = rowp[off + 2];
      }
      tagB[t] = (unsigned char)tag;
      uint32_t sel = (tag < 4) ? (r0 >> (tag * 8))
                   : (tag < 8) ? (r1 >> ((tag - 4) * 8))
                               : (r2 >> ((tag - 8) * 8));
      tag = (int)(sel & 0xffu);
      r0 = n0; r1 = n1; r2 = n2;
    }
  }
  __syncthreads();
  for (int t = lane; t < 512; t += 64) out[64 + (size_t)b * 512 + t] = (float)tagB[t];
}

extern "C" void kernel_launch(void* const* d_in, const int* in_sizes, int n_in,
                              void* d_out, int out_size, void* d_ws, size_t ws_size,
                              hipStream_t stream) {
  (void)in_sizes; (void)n_in; (void)out_size; (void)ws_size;
  const int* sentence = (const int*)d_in[0];
  const int* seq_lens = (const int*)d_in[1];
  const float* embed = (const float*)d_in[2];
  const float* Wi_f = (const float*)d_in[3];
  const float* Wh_f = (const float*)d_in[4];
  const float* b_f = (const float*)d_in[5];
  const float* Wi_b = (const float*)d_in[6];
  const float* Wh_b = (const float*)d_in[7];
  const float* b_b = (const float*)d_in[8];
  const float* h0 = (const float*)d_in[9];
  const float* c0 = (const float*)d_in[10];
  const float* W_out = (const float*)d_in[11];
  const float* b_out = (const float*)d_in[12];
  const float* trans = (const float*)d_in[13];

  char* ws = (char*)d_ws;
  unsigned* bar = (unsigned*)ws;
  unsigned long long* featsFix = (unsigned long long*)(ws + FEATS_OFF);
  float* hbuf = (float*)(ws + HBUF_OFF);
  float* cbuf = (float*)(ws + CBUF_OFF);
  unsigned char* bps = (unsigned char*)(ws + BPS_OFF);
  float* xpw = (float*)(ws + XP_OFF);
  float* xpw2 = (float*)(ws + XP2_OFF);

  hipMemsetAsync(d_ws, 0, FEATS_OFF + FEATS_BYTES, stream);

  hipFuncSetAttribute((const void*)lstm_phase,
                      hipFuncAttributeMaxDynamicSharedMemorySize, LSTM_SMEM_BYTES);
  hipFuncSetAttribute((const void*)pre_gemm,
                      hipFuncAttributeMaxDynamicSharedMemorySize, PRE_SMEM_BYTES);

  init_state<<<dim3(512), dim3(256), 0, stream>>>(h0, c0, hbuf, cbuf);

  for (int p = 0; p < NPH; ++p) {
    pre_gemm<<<dim3(256, 8), dim3(BLK), PRE_SMEM_BYTES, stream>>>(
        p, sentence, seq_lens, embed, Wi_f, Wi_b, xpw, xpw2);
    int pv = p;
    void* kargs[] = {(void*)&pv,   (void*)&seq_lens, (void*)&Wh_f,  (void*)&Wh_b,
                     (void*)&b_f,  (void*)&b_b,      (void*)&W_out, (void*)&xpw,
                     (void*)&xpw2, (void*)&hbuf,     (void*)&cbuf,  (void*)&featsFix,
                     (void*)&bar};
    hipLaunchCooperativeKernel((const void*)lstm_phase, dim3(NWG), dim3(BLK), kargs,
                               LSTM_SMEM_BYTES, stream);
  }
  viterbi2<<<dim3(64), dim3(64), 0, stream>>>(seq_lens, b_out, trans, featsFix, bps,
                                              (float*)d_out);
}